// Round 12
// baseline (1330.801 us; speedup 1.0000x reference)
//
#include <hip/hip_runtime.h>

typedef _Float16 f16;
typedef _Float16 f16x8 __attribute__((ext_vector_type(8)));
typedef float f32x4 __attribute__((ext_vector_type(4)));
typedef float f32x16 __attribute__((ext_vector_type(16)));
typedef unsigned int u32;
typedef u32 u32x4 __attribute__((ext_vector_type(4)));

#define SEQ 512
#define BATCH 256
#define DIN 512
#define DH 1024
#define DK 1536
#define NCLS 1000

#define NGROUP 8      // groups == physical XCDs (dynamic via HW_REG_XCC_ID)
#define ROWS 32
#define OUTS 32
#define KSLICES 96
#define RED_STRIDE 33

#define SMEM_ALLOC (96 * 1024)   // pigeonhole: 1 WG/CU -> 32 WGs per XCD

// watchdogs: poll loops can never hang the 600s harness (fast wrong answer).
#define POLL_GUARD  8192         // fallback tag-poll retries
#define FLAG_GUARD  (1 << 17)    // flag-poll retries (~5ms/step worst case)

// LDS map: two 32KB x-frag buffers | red | blds | meta
#define XLDS1_OFF 32768
#define RED_OFF3  65536
#define RED_BYTES (4 * OUTS * RED_STRIDE * 4)
#define BLDS_OFF  (RED_OFF3 + RED_BYTES)
#define META_OFF  (BLDS_OFF + OUTS * 4)

// ws map
#define WF_OFF     0
#define HP_OFF     ((size_t)4 << 20)
#define HP_GROUP   65536                            // 64 frags x 1KB
#define HP_HALF    ((size_t)NGROUP * HP_GROUP)      // 512 KB
#define HP_BYTES   (2 * HP_HALF)
#define FLG_OFF    ((size_t)6 << 20)
#define FLG_BYTES  (NGROUP * 32 * 128)              // one 128B line per producer WG
#define SLOT_OFF   (FLG_OFF + 65536)
#define SLOT_BYTES (NGROUP * 64)
#define XF_OFF     ((size_t)8 << 20)
#define XF_BYTES   ((size_t)SEQ * NGROUP * 32 * 1024)   // 128 MB
#define WS_NEED    (XF_OFF + XF_BYTES)

// tag bits: used ONLY by the !XF fallback (R6 protocol)
#define TAGBITS 0x40004000u
#define STRIPM  0xBFFFBFFFu

// ---- XCD-local L2-scope access (sc0 = bypass L1; group lives on one XCD) ----
__device__ __forceinline__ u32x4 hload4(const void* p) {
    u32x4 v;
    asm volatile("global_load_dwordx4 %0, %1, off sc0" : "=v"(v) : "v"(p) : "memory");
    return v;
}
__device__ __forceinline__ void hstore8(void* p, uint2 v) {
    asm volatile("global_store_dwordx2 %0, %1, off sc0" :: "v"(p), "v"(v) : "memory");
}
__device__ __forceinline__ u32 flag_poll_load(const u32* p) {
    u32 v;
    asm volatile("global_load_dword %0, %1, off sc0\n\ts_waitcnt vmcnt(0)"
                 : "=v"(v) : "v"(p) : "memory");
    return v;
}
__device__ __forceinline__ void flag_store(u32* p, u32 v) {
    asm volatile("global_store_dword %0, %1, off sc0" :: "v"(p), "v"(v) : "memory");
}
// async global->LDS, 16B per lane; LDS dest = wave-uniform base + lane*16
__device__ __forceinline__ void glds16(const void* gsrc, void* ldst) {
    __builtin_amdgcn_global_load_lds(
        (const __attribute__((address_space(1))) u32*)gsrc,
        (__attribute__((address_space(3))) u32*)ldst, 16, 0, 0);
}
__device__ __forceinline__ void barrier_lgkm_only() {
    __builtin_amdgcn_sched_barrier(0);
    asm volatile("s_waitcnt lgkmcnt(0)" ::: "memory");
    __builtin_amdgcn_s_barrier();
    asm volatile("" ::: "memory");
    __builtin_amdgcn_sched_barrier(0);
}

// ---- W [1024][1536] fp32 -> f16 A-fragment-linear layout ----
// Wf[((s*96 + j)*64 + lane)*8 + v] = W[s*32 + (lane&31)][j*16 + (lane>>5)*8 + v]
__global__ void __launch_bounds__(256) convert_W_kernel(const float* __restrict__ W,
                                                        f16* __restrict__ Wf) {
    int id = blockIdx.x * 256 + threadIdx.x;
    if (id >= DH * DK) return;
    int v = id & 7;
    int l = (id >> 3) & 63;
    int rest = id >> 9;
    int j = rest % KSLICES;
    int s = rest / KSLICES;
    int row = s * OUTS + (l & 31);
    int k = j * 16 + ((l >> 5) << 3) + v;
    Wf[id] = (f16)W[row * DK + k];
}

// ---- x [SEQ][BATCH][DIN] f32 -> fragment-packed f16 xf[t][g][j][lane][16B] ----
__global__ void __launch_bounds__(256) convert_x_kernel(const float* __restrict__ x,
                                                        f16* __restrict__ xf) {
    __shared__ f16 tile[ROWS * DIN];   // 32 KB
    const int tid = threadIdx.x;
    const float* src = x + (size_t)blockIdx.x * (ROWS * DIN);  // blockIdx = t*8+g
#pragma unroll
    for (int c = 0; c < 16; ++c) {
        int off = (c * 256 + tid) * 4;
        f32x4 a = *(const f32x4*)(src + off);
        union { f16 h[4]; uint2 u; } uu;
        uu.h[0] = (f16)a[0]; uu.h[1] = (f16)a[1]; uu.h[2] = (f16)a[2]; uu.h[3] = (f16)a[3];
        *(uint2*)&tile[off] = uu.u;
    }
    __syncthreads();
    char* dst = (char*)xf + (size_t)blockIdx.x * 32768 + tid * 128;
    int j = tid >> 3;
    int l0 = (tid & 7) * 8;
    f16x8 buf[8];
#pragma unroll
    for (int e = 0; e < 8; ++e) {
        int l = l0 + e;
        buf[e] = *(const f16x8*)&tile[(l & 31) * DIN + j * 16 + (l >> 5) * 8];
    }
#pragma unroll
    for (int e = 0; e < 8; ++e) *(f16x8*)(dst + e * 16) = buf[e];
}

// ---- persistent RNN kernel: 256 WGs, grouped by physical XCD ----
// XF=true : x pre-packed f16 frags via global_load_lds (double-buffered);
//           h sync = per-producer flag lines, ONE polling wave per WG,
//           single-sweep h read with clean vmcnt split.
// XF=false: R6/R11 fallback — tag-in-data protocol, f32 x staged via LDS.
template<bool XF>
__global__ void __launch_bounds__(256, 1)
rnn_kernel(const float* __restrict__ x, const float* __restrict__ bias,
           const f16* __restrict__ Wf, const f16* __restrict__ xf,
           f16* __restrict__ hpack, u32* __restrict__ flags,
           int* __restrict__ xslots) {
    extern __shared__ char smem[];
    char*  xlds = smem;
    float* red  = (float*)(smem + RED_OFF3);
    float* blds = (float*)(smem + BLDS_OFF);
    int*   meta = (int*)(smem + META_OFF);

    const int tid  = threadIdx.x;
    const int wave = tid >> 6;
    const int lane = tid & 63;
    const int r    = lane & 31;
    const int hi   = lane >> 5;

    if (tid == 0) {
        u32 xcc;
        asm volatile("s_getreg_b32 %0, hwreg(HW_REG_XCC_ID)" : "=s"(xcc));
        meta[0] = (int)(xcc & 7);
        meta[1] = atomicAdd(&xslots[xcc & 7], 1) & 31;
    }
    __syncthreads();
    const int g = meta[0];
    const int s = meta[1];
    if (tid < OUTS) blds[tid] = bias[s * OUTS + tid];

    // weight A-fragments -> registers (96 VGPRs/lane)
    f16x8 wf[24];
    {
        const f16x8* wp = ((const f16x8*)Wf) + (size_t)s * KSLICES * 64 + lane;
#pragma unroll
        for (int i = 0; i < 24; ++i) wf[i] = wp[(size_t)(wave + 4 * i) * 64];
    }

    // flag lines: one 128B line (32 dwords) per producer WG of this group.
    // wave0's lane l polls line l>>1 (2 lanes/line, 32 lines).
    const u32* fpoll = flags + ((size_t)g * 32 + (lane >> 1)) * 32;
    u32* fmine = flags + ((size_t)g * 32 + s) * 32;

    // finish-phase assignment
    const int b_ = tid >> 3, o0 = (tid & 7) * 4;
    const int fj = (s << 1) + (o0 >> 4);
    const size_t foff = (size_t)fj * 1024 + ((((o0 >> 3) & 1) << 5) + b_) * 16 + (o0 & 7) * 2;

    // fallback staging vars (R6)
    const int srow = tid >> 6, scol = (tid & 63) * 8;
    const int sj = scol >> 4, shi = (scol >> 3) & 1, sswz = (sj & 7) << 4;

    union cvt_t { u32x4 u; f16x8 h; };

    // ---- prologue (XF): stage x(0) into xlds buf0 via global_load_lds ----
    if constexpr (XF) {
        const char* xg = (const char*)xf + (size_t)g * 32768 + lane * 16;
#pragma unroll
        for (int i = 0; i < 8; ++i) {
            int j = wave + 4 * i;
            glds16(xg + j * 1024, xlds + j * 1024);
        }
        asm volatile("s_waitcnt vmcnt(0)" ::: "memory");
        __syncthreads();
    }

    for (int t = 0; t < SEQ; ++t) {
        // ---- 0. (fallback) stage x(t): f32 -> f16 -> swizzled LDS ----
        if constexpr (!XF) {
            const float* xt = x + ((size_t)t * BATCH + g * ROWS) * DIN;
#pragma unroll
            for (int i = 0; i < 8; ++i) {
                int row = srow + 4 * i;
                const float* xp = xt + row * DIN + scol;
                f32x4 a0 = *(const f32x4*)xp;
                f32x4 a1 = *(const f32x4*)(xp + 4);
                f16x8 o;
                o[0] = (f16)a0[0]; o[1] = (f16)a0[1]; o[2] = (f16)a0[2]; o[3] = (f16)a0[3];
                o[4] = (f16)a1[0]; o[5] = (f16)a1[1]; o[6] = (f16)a1[2]; o[7] = (f16)a1[3];
                *(f16x8*)(xlds + ((sj * 1024 + ((shi << 5) + row) * 16) ^ sswz)) = o;
            }
            __syncthreads();
        }

        f32x16 accA = {0,0,0,0, 0,0,0,0, 0,0,0,0, 0,0,0,0};
        f32x16 accB = {0,0,0,0, 0,0,0,0, 0,0,0,0, 0,0,0,0};

        // ---- 1. x-MFMA from LDS (buffer ready: drained at prev step's barriers) ----
        if constexpr (XF) { asm volatile("s_waitcnt vmcnt(0)" ::: "memory");
                            __builtin_amdgcn_sched_barrier(0); }
        {
            const char* xc = xlds + (XF ? (t & 1) * XLDS1_OFF : 0);
#pragma unroll
            for (int i = 0; i < 8; ++i) {
                int j = wave + 4 * i;
                f16x8 bf;
                if constexpr (XF)
                    bf = *(const f16x8*)(xc + j * 1024 + lane * 16);
                else
                    bf = *(const f16x8*)(xc + ((j * 1024 + lane * 16) ^ ((j & 7) << 4)));
                if (i & 1) accB = __builtin_amdgcn_mfma_f32_32x32x16_f16(wf[i], bf, accB, 0, 0, 0);
                else       accA = __builtin_amdgcn_mfma_f32_32x32x16_f16(wf[i], bf, accA, 0, 0, 0);
            }
        }

        // ---- 2. (XF) async-prefetch x(t+1) into the other LDS buffer ----
        if constexpr (XF) {
            int tn = t + 1; if (tn == SEQ) tn = SEQ - 1;
            const char* xg = (const char*)xf + (size_t)(tn * NGROUP + g) * 32768 + lane * 16;
            char* xn = xlds + ((t + 1) & 1) * XLDS1_OFF;
#pragma unroll
            for (int i = 0; i < 8; ++i) {
                int j = wave + 4 * i;
                glds16(xg + j * 1024, xn + j * 1024);
            }
        }

        // ---- 3. h-part ----
        if constexpr (XF) {
            // wave0 polls 32 per-producer flag lines; other waves park at the
            // barrier (its implicit vmcnt(0) also drains the glds prefetch).
            if (wave == 0) {
                int guard = FLAG_GUARD;
                for (;;) {
                    u32 v = flag_poll_load(fpoll);
                    if (__all(v >= (u32)t)) break;
                    if (--guard == 0) break;           // watchdog: fast wrong answer
                    __builtin_amdgcn_s_sleep(1);
                }
            }
            __syncthreads();   // release: h(t) visible in L2 for the whole WG

            // single sweep: vmcnt is 0 here (barrier drained) -> clean counting
            const char* hpb = (const char*)hpack + (size_t)((t & 1) * NGROUP + g) * HP_GROUP
                            + wave * 1024 + lane * 16;
            u32x4 hvA[8], hvB[8];
#pragma unroll
            for (int q = 0; q < 8; ++q) hvA[q] = hload4(hpb + q * 4096);
#pragma unroll
            for (int q = 0; q < 8; ++q) hvB[q] = hload4(hpb + 32768 + q * 4096);
            asm volatile("s_waitcnt vmcnt(8)" ::: "memory");
            __builtin_amdgcn_sched_barrier(0);
#pragma unroll
            for (int q = 0; q < 8; ++q) {
                cvt_t c; c.u = hvA[q];
                if (q & 1) accB = __builtin_amdgcn_mfma_f32_32x32x16_f16(wf[8 + q], c.h, accB, 0, 0, 0);
                else       accA = __builtin_amdgcn_mfma_f32_32x32x16_f16(wf[8 + q], c.h, accA, 0, 0, 0);
            }
            asm volatile("s_waitcnt vmcnt(0)" ::: "memory");
            __builtin_amdgcn_sched_barrier(0);
#pragma unroll
            for (int q = 0; q < 8; ++q) {
                cvt_t c; c.u = hvB[q];
                if (q & 1) accB = __builtin_amdgcn_mfma_f32_32x32x16_f16(wf[16 + q], c.h, accB, 0, 0, 0);
                else       accA = __builtin_amdgcn_mfma_f32_32x32x16_f16(wf[16 + q], c.h, accA, 0, 0, 0);
            }
        } else {
            // R6/R11 tag-in-data protocol with watchdog (validated fallback)
            const char* hpb = (const char*)hpack + (size_t)((t & 1) * NGROUP + g) * HP_GROUP
                            + wave * 1024 + lane * 16;
            const u32 rtag = (u32)((t >> 1) & 1);
#pragma unroll
            for (int hh = 0; hh < 2; ++hh) {
                const char* pb = hpb + hh * 32768;
                u32x4 hv[8];
                int guard = POLL_GUARD;
                if (rtag == 0) {
                    for (;;) {
#pragma unroll
                        for (int q = 0; q < 8; ++q) hv[q] = hload4(pb + q * 4096);
                        asm volatile("s_waitcnt vmcnt(0)" ::: "memory");
                        __builtin_amdgcn_sched_barrier(0);
                        u32 orr = 0;
#pragma unroll
                        for (int q = 0; q < 8; ++q) orr |= hv[q].x | hv[q].y | hv[q].z | hv[q].w;
                        if (__all((orr & TAGBITS) == 0u)) break;
                        if (--guard == 0) break;
                    }
                } else {
                    for (;;) {
#pragma unroll
                        for (int q = 0; q < 8; ++q) hv[q] = hload4(pb + q * 4096);
                        asm volatile("s_waitcnt vmcnt(0)" ::: "memory");
                        __builtin_amdgcn_sched_barrier(0);
                        u32 andv = 0xFFFFFFFFu;
#pragma unroll
                        for (int q = 0; q < 8; ++q) andv &= hv[q].x & hv[q].y & hv[q].z & hv[q].w;
                        if (__all((andv & TAGBITS) == TAGBITS)) break;
                        if (--guard == 0) break;
                    }
#pragma unroll
                    for (int q = 0; q < 8; ++q) hv[q] &= STRIPM;
                }
                __builtin_amdgcn_sched_barrier(0);
#pragma unroll
                for (int q = 0; q < 8; ++q) {
                    cvt_t c; c.u = hv[q];
                    if (q & 1) accB = __builtin_amdgcn_mfma_f32_32x32x16_f16(wf[8 + 8 * hh + q], c.h, accB, 0, 0, 0);
                    else       accA = __builtin_amdgcn_mfma_f32_32x32x16_f16(wf[8 + 8 * hh + q], c.h, accA, 0, 0, 0);
                }
            }
        }

        // ---- 4. K-split partials -> LDS ----
        {
            float* rw = red + wave * (OUTS * RED_STRIDE);
            int rb = hi << 2;
#pragma unroll
            for (int v = 0; v < 16; ++v) {
                int orow = (v & 3) + 8 * (v >> 2) + rb;
                rw[orow * RED_STRIDE + r] = accA[v] + accB[v];
            }
        }
        if constexpr (XF) barrier_lgkm_only();   // red ready; glds already drained
        else              __syncthreads();

        // ---- 5. finish: reduce 4 partials + bias, fast tanh, store h ----
        {
            char* hob = (char*)hpack + (size_t)(((t + 1) & 1) * NGROUP + g) * HP_GROUP + foff;
            union { f16 h4[4]; uint2 u; } uu;
#pragma unroll
            for (int i = 0; i < 4; ++i) {
                int o = o0 + i;
                float p = blds[o];
#pragma unroll
                for (int w2 = 0; w2 < 4; ++w2)
                    p += red[w2 * (OUTS * RED_STRIDE) + o * RED_STRIDE + b_];
                // tanh(p) = 1 - 2/(e^{2p}+1)
                float e = __expf(2.f * p);
                uu.h4[i] = (f16)(1.f - 2.f / (e + 1.f));
            }
            if constexpr (XF) {
                hstore8(hob, uu.u);
            } else {
                const u32 wtag = (u32)(((t + 1) >> 1) & 1);
                if (wtag) { uu.u.x |= TAGBITS; uu.u.y |= TAGBITS; }
                hstore8(hob, uu.u);
            }
        }

        if constexpr (XF) {
            // full barrier: drains every wave's h stores to L2 (coherence
            // point) and protects red[] WAR; then publish cumulative flag.
            __syncthreads();
            if (tid == 0) flag_store(fmine, (u32)(t + 1));
        } else {
            barrier_lgkm_only();
        }
    }
}

// ---- classify: block per class, thread per batch row (packed buf 0) ----
__global__ void __launch_bounds__(256) classify_kernel(const f16* __restrict__ hpack,
                                                       const float* __restrict__ Wc,
                                                       const float* __restrict__ bc,
                                                       float* __restrict__ out) {
    __shared__ float wrow[DH];
    int c = blockIdx.x;
    int tid = threadIdx.x;
    for (int i = tid; i < DH; i += 256) wrow[i] = Wc[(size_t)c * DH + i];
    __syncthreads();
    int g = tid >> 5, r2 = tid & 31;
    const char* base = (const char*)hpack + (size_t)g * HP_GROUP;   // buffer 0
    float acc = bc[c];
    for (int j = 0; j < 64; ++j) {
#pragma unroll
        for (int h2 = 0; h2 < 2; ++h2) {
            f16x8 hv = *(const f16x8*)(base + j * 1024 + ((h2 << 5) + r2) * 16);
            int k = j * 16 + h2 * 8;
#pragma unroll
            for (int v = 0; v < 8; ++v) acc += (float)hv[v] * wrow[k + v];
        }
    }
    out[(size_t)tid * NCLS + c] = acc;
}

extern "C" void kernel_launch(void* const* d_in, const int* in_sizes, int n_in,
                              void* d_out, int out_size, void* d_ws, size_t ws_size,
                              hipStream_t stream) {
    const float* x  = (const float*)d_in[0];
    const float* W  = (const float*)d_in[1];
    const float* b  = (const float*)d_in[2];
    const float* Wc = (const float*)d_in[3];
    const float* bc = (const float*)d_in[4];
    float* out = (float*)d_out;

    char* ws = (char*)d_ws;
    f16* Wf     = (f16*)(ws + WF_OFF);
    f16* hpack  = (f16*)(ws + HP_OFF);
    u32* flags  = (u32*)(ws + FLG_OFF);
    int* xslots = (int*)(ws + SLOT_OFF);
    f16* xf     = (f16*)(ws + XF_OFF);

    const bool bigws = (ws_size >= WS_NEED);

    // buffer 0: zeros = h0 (valid).  buffer 1: 0x4040 stale pattern (only the
    // fallback's tag protocol needs it; harmless for XF).  flags cumulative
    // from 0; slots zeroed.  All re-done every call (graph replays).
    hipMemsetAsync(hpack, 0, HP_HALF, stream);
    hipMemsetAsync((char*)hpack + HP_HALF, 0x40, HP_HALF, stream);
    hipMemsetAsync(flags, 0, FLG_BYTES, stream);
    hipMemsetAsync(xslots, 0, SLOT_BYTES, stream);

    convert_W_kernel<<<(DH * DK + 255) / 256, 256, 0, stream>>>(W, Wf);
    if (bigws)
        convert_x_kernel<<<dim3(SEQ * NGROUP), dim3(256), 0, stream>>>(x, xf);

    const void* kfn = bigws ? (const void*)rnn_kernel<true>
                            : (const void*)rnn_kernel<false>;
    hipFuncSetAttribute(kfn, hipFuncAttributeMaxDynamicSharedMemorySize, SMEM_ALLOC);
    void* args[7];
    args[0] = (void*)&x;
    args[1] = (void*)&b;
    args[2] = (void*)&Wf;
    args[3] = (void*)&xf;
    args[4] = (void*)&hpack;
    args[5] = (void*)&flags;
    args[6] = (void*)&xslots;
    hipLaunchCooperativeKernel(kfn, dim3(256), dim3(256), args, SMEM_ALLOC, stream);

    // final h in packed buffer 0 (step 511 writes buf (512)&1 = 0)
    classify_kernel<<<dim3(NCLS), dim3(256), 0, stream>>>(hpack, Wc, bc, out);
}

// Round 16
// 1221.316 us; speedup vs baseline: 1.0896x; 1.0896x over previous
//
#include <hip/hip_runtime.h>

typedef _Float16 f16;
typedef _Float16 f16x8 __attribute__((ext_vector_type(8)));
typedef float f32x4 __attribute__((ext_vector_type(4)));
typedef float f32x16 __attribute__((ext_vector_type(16)));
typedef unsigned int u32;
typedef u32 u32x4 __attribute__((ext_vector_type(4)));

#define SEQ 512
#define BATCH 256
#define DIN 512
#define DH 1024
#define DK 1536
#define NCLS 1000

#define NGROUP 8      // groups == physical XCDs (dynamic via HW_REG_XCC_ID)
#define ROWS 32
#define OUTS 32
#define KSLICES 96
#define RED_STRIDE 33

#define SMEM_ALLOC (96 * 1024)   // pigeonhole: 1 WG/CU -> 32 WGs per XCD

// poll watchdog: normal waits are ~10-20 retries; 8192 is ~1000x margin.
// If it fires, results are wrong (fast-fail) but the harness never hangs.
#define POLL_GUARD 8192

// LDS map: two 32KB x-frag buffers | red | blds | meta
#define XLDS1_OFF 32768
#define RED_OFF3  65536
#define RED_BYTES (4 * OUTS * RED_STRIDE * 4)
#define BLDS_OFF  (RED_OFF3 + RED_BYTES)
#define META_OFF  (BLDS_OFF + OUTS * 4)

// ws map
#define WF_OFF     0
#define HP_OFF     ((size_t)4 << 20)
#define HP_GROUP   65536                            // 64 frags x 1KB
#define HP_HALF    ((size_t)NGROUP * HP_GROUP)      // 512 KB
#define HP_BYTES   (2 * HP_HALF)
#define SLOT_OFF   ((size_t)6 << 20)
#define SLOT_BYTES (NGROUP * 64)
#define XF_OFF     ((size_t)8 << 20)
#define XF_BYTES   ((size_t)SEQ * NGROUP * 32 * 1024)   // 128 MB
#define WS_NEED    (XF_OFF + XF_BYTES)

// tag bit: f16 bit14. tanh output |h|<=1 -> bit14 always 0 in real data.
#define TAGBITS 0x40004000u
#define STRIPM  0xBFFFBFFFu

// EMPIRICAL RULE (R8/R11/R12 pass vs R13/R14/R15 fail): global_load_lds
// prefetches must be issued BEFORE the tag-poll; the poll's s_waitcnt
// vmcnt(0) is their drain. Issuing them after the poll corrupts the
// x-path regardless of drain style (counted, vmcnt(0), vmcnt(0)+barrier).

// ---- XCD-local L2-scope access (sc0 = bypass L1; group lives on one XCD) ----
__device__ __forceinline__ u32x4 hload4(const void* p) {
    u32x4 v;
    asm volatile("global_load_dwordx4 %0, %1, off sc0" : "=v"(v) : "v"(p) : "memory");
    return v;
}
__device__ __forceinline__ void hstore8(void* p, uint2 v) {
    asm volatile("global_store_dwordx2 %0, %1, off sc0" :: "v"(p), "v"(v) : "memory");
}
// async global->LDS, 16B per lane; LDS dest = wave-uniform base + lane*16
__device__ __forceinline__ void glds16(const void* gsrc, void* ldst) {
    __builtin_amdgcn_global_load_lds(
        (const __attribute__((address_space(1))) u32*)gsrc,
        (__attribute__((address_space(3))) u32*)ldst, 16, 0, 0);
}
__device__ __forceinline__ void barrier_lgkm_only() {
    __builtin_amdgcn_sched_barrier(0);
    asm volatile("s_waitcnt lgkmcnt(0)" ::: "memory");
    __builtin_amdgcn_s_barrier();
    asm volatile("" ::: "memory");
    __builtin_amdgcn_sched_barrier(0);
}

// ---- W [1024][1536] fp32 -> f16 A-fragment-linear layout ----
// Wf[((s*96 + j)*64 + lane)*8 + v] = W[s*32 + (lane&31)][j*16 + (lane>>5)*8 + v]
__global__ void __launch_bounds__(256) convert_W_kernel(const float* __restrict__ W,
                                                        f16* __restrict__ Wf) {
    int id = blockIdx.x * 256 + threadIdx.x;
    if (id >= DH * DK) return;
    int v = id & 7;
    int l = (id >> 3) & 63;
    int rest = id >> 9;
    int j = rest % KSLICES;
    int s = rest / KSLICES;
    int row = s * OUTS + (l & 31);
    int k = j * 16 + ((l >> 5) << 3) + v;
    Wf[id] = (f16)W[row * DK + k];
}

// ---- x [SEQ][BATCH][DIN] f32 -> fragment-packed f16 xf[t][g][j][lane][16B] ----
__global__ void __launch_bounds__(256) convert_x_kernel(const float* __restrict__ x,
                                                        f16* __restrict__ xf) {
    __shared__ f16 tile[ROWS * DIN];   // 32 KB
    const int tid = threadIdx.x;
    const float* src = x + (size_t)blockIdx.x * (ROWS * DIN);  // blockIdx = t*8+g
#pragma unroll
    for (int c = 0; c < 16; ++c) {
        int off = (c * 256 + tid) * 4;
        f32x4 a = *(const f32x4*)(src + off);
        union { f16 h[4]; uint2 u; } uu;
        uu.h[0] = (f16)a[0]; uu.h[1] = (f16)a[1]; uu.h[2] = (f16)a[2]; uu.h[3] = (f16)a[3];
        *(uint2*)&tile[off] = uu.u;
    }
    __syncthreads();
    char* dst = (char*)xf + (size_t)blockIdx.x * 32768 + tid * 128;
    int j = tid >> 3;
    int l0 = (tid & 7) * 8;
    f16x8 buf[8];
#pragma unroll
    for (int e = 0; e < 8; ++e) {
        int l = l0 + e;
        buf[e] = *(const f16x8*)&tile[(l & 31) * DIN + j * 16 + (l >> 5) * 8];
    }
#pragma unroll
    for (int e = 0; e < 8; ++e) *(f16x8*)(dst + e * 16) = buf[e];
}

// ---- persistent RNN kernel: 256 WGs, grouped by physical XCD ----
// XF=true : x pre-packed f16 frags staged via global_load_lds, double-buffered.
//           glds issued at TOP of step (before x-MFMA, before poll): its
//           flight overlaps the x-MFMA, and the poll's vmcnt(0) drains it.
// XF=false: R6 fallback — f32 x staged via regs->swizzled LDS each step.
// h exchange: tag-in-data (bit14 generation tags) through XCD-local L2.
template<bool XF>
__global__ void __launch_bounds__(256, 1)
rnn_kernel(const float* __restrict__ x, const float* __restrict__ bias,
           const f16* __restrict__ Wf, const f16* __restrict__ xf,
           f16* __restrict__ hpack, int* __restrict__ xslots) {
    extern __shared__ char smem[];
    char*  xlds = smem;
    float* red  = (float*)(smem + RED_OFF3);
    float* blds = (float*)(smem + BLDS_OFF);
    int*   meta = (int*)(smem + META_OFF);

    const int tid  = threadIdx.x;
    const int wave = tid >> 6;
    const int lane = tid & 63;
    const int r    = lane & 31;
    const int hi   = lane >> 5;

    if (tid == 0) {
        u32 xcc;
        asm volatile("s_getreg_b32 %0, hwreg(HW_REG_XCC_ID)" : "=s"(xcc));
        meta[0] = (int)(xcc & 7);
        meta[1] = atomicAdd(&xslots[xcc & 7], 1) & 31;
    }
    __syncthreads();
    const int g = meta[0];
    const int s = meta[1];
    if (tid < OUTS) blds[tid] = bias[s * OUTS + tid];

    // weight A-fragments -> registers (96 VGPRs/lane)
    f16x8 wf[24];
    {
        const f16x8* wp = ((const f16x8*)Wf) + (size_t)s * KSLICES * 64 + lane;
#pragma unroll
        for (int i = 0; i < 24; ++i) wf[i] = wp[(size_t)(wave + 4 * i) * 64];
    }

    // finish-phase assignment
    const int b_ = tid >> 3, o0 = (tid & 7) * 4;
    const int fj = (s << 1) + (o0 >> 4);
    const size_t foff = (size_t)fj * 1024 + ((((o0 >> 3) & 1) << 5) + b_) * 16 + (o0 & 7) * 2;

    // fallback staging vars (R6)
    const int srow = tid >> 6, scol = (tid & 63) * 8;
    const int sj = scol >> 4, shi = (scol >> 3) & 1, sswz = (sj & 7) << 4;

    union cvt_t { u32x4 u; f16x8 h; };

    // ---- prologue (XF): stage x(0) into xlds buf0 via global_load_lds ----
    if constexpr (XF) {
        const char* xg = (const char*)xf + (size_t)g * 32768 + lane * 16;
#pragma unroll
        for (int i = 0; i < 8; ++i) {
            int j = wave + 4 * i;
            glds16(xg + j * 1024, xlds + j * 1024);
        }
        asm volatile("s_waitcnt vmcnt(0)" ::: "memory");
        __syncthreads();
    }

    for (int t = 0; t < SEQ; ++t) {
        // ---- 0. (fallback) stage x(t): f32 -> f16 -> swizzled LDS ----
        if constexpr (!XF) {
            const float* xt = x + ((size_t)t * BATCH + g * ROWS) * DIN;
#pragma unroll
            for (int i = 0; i < 8; ++i) {
                int row = srow + 4 * i;
                const float* xp = xt + row * DIN + scol;
                f32x4 a0 = *(const f32x4*)xp;
                f32x4 a1 = *(const f32x4*)(xp + 4);
                f16x8 o;
                o[0] = (f16)a0[0]; o[1] = (f16)a0[1]; o[2] = (f16)a0[2]; o[3] = (f16)a0[3];
                o[4] = (f16)a1[0]; o[5] = (f16)a1[1]; o[6] = (f16)a1[2]; o[7] = (f16)a1[3];
                *(f16x8*)(xlds + ((sj * 1024 + ((shi << 5) + row) * 16) ^ sswz)) = o;
            }
            __syncthreads();
        }

        // ---- 1. (XF) async-prefetch x(t+1) FIRST: overlaps the x-MFMA below,
        //         then the poll's vmcnt(0) drains it (glds-before-poll class,
        //         the only empirically safe placement — see rule above).
        //         buf((t+1)&1) WAR-safe: last read at t-1 phase 2, two
        //         barriers ago. ----
        if constexpr (XF) {
            int tn = t + 1; if (tn == SEQ) tn = SEQ - 1;
            const char* xg = (const char*)xf + (size_t)(tn * NGROUP + g) * 32768 + lane * 16;
            char* xn = xlds + ((t + 1) & 1) * XLDS1_OFF;
#pragma unroll
            for (int i = 0; i < 8; ++i) {
                int j = wave + 4 * i;
                glds16(xg + j * 1024, xn + j * 1024);
            }
        }

        f32x16 accA = {0,0,0,0, 0,0,0,0, 0,0,0,0, 0,0,0,0};
        f32x16 accB = {0,0,0,0, 0,0,0,0, 0,0,0,0, 0,0,0,0};

        // ---- 2. x-MFMA from LDS (buf(t&1): staged last step, drained by
        //         last step's poll vmcnt(0) + two barriers) ----
        {
            const char* xc = xlds + (XF ? (t & 1) * XLDS1_OFF : 0);
#pragma unroll
            for (int i = 0; i < 8; ++i) {
                int j = wave + 4 * i;
                f16x8 bf;
                if constexpr (XF)
                    bf = *(const f16x8*)(xc + j * 1024 + lane * 16);
                else
                    bf = *(const f16x8*)(xc + ((j * 1024 + lane * 16) ^ ((j & 7) << 4)));
                if (i & 1) accB = __builtin_amdgcn_mfma_f32_32x32x16_f16(wf[i], bf, accB, 0, 0, 0);
                else       accA = __builtin_amdgcn_mfma_f32_32x32x16_f16(wf[i], bf, accA, 0, 0, 0);
            }
        }

        // ---- 3. h-part: poll the tagged data itself (validated protocol).
        //         First retry's vmcnt(0) also drains the glds above. ----
        {
            const char* hpb = (const char*)hpack + (size_t)((t & 1) * NGROUP + g) * HP_GROUP
                            + wave * 1024 + lane * 16;
            const u32 rtag = (u32)((t >> 1) & 1);
#pragma unroll
            for (int hh = 0; hh < 2; ++hh) {
                const char* pb = hpb + hh * 32768;
                u32x4 hv[8];
                int guard = POLL_GUARD;
                if (rtag == 0) {
                    for (;;) {
#pragma unroll
                        for (int q = 0; q < 8; ++q) hv[q] = hload4(pb + q * 4096);
                        asm volatile("s_waitcnt vmcnt(0)" ::: "memory");
                        __builtin_amdgcn_sched_barrier(0);
                        u32 orr = 0;
#pragma unroll
                        for (int q = 0; q < 8; ++q) orr |= hv[q].x | hv[q].y | hv[q].z | hv[q].w;
                        if (__all((orr & TAGBITS) == 0u)) break;
                        if (--guard == 0) break;   // watchdog: never hang the harness
                    }
                } else {
                    for (;;) {
#pragma unroll
                        for (int q = 0; q < 8; ++q) hv[q] = hload4(pb + q * 4096);
                        asm volatile("s_waitcnt vmcnt(0)" ::: "memory");
                        __builtin_amdgcn_sched_barrier(0);
                        u32 andv = 0xFFFFFFFFu;
#pragma unroll
                        for (int q = 0; q < 8; ++q) andv &= hv[q].x & hv[q].y & hv[q].z & hv[q].w;
                        if (__all((andv & TAGBITS) == TAGBITS)) break;
                        if (--guard == 0) break;   // watchdog
                    }
#pragma unroll
                    for (int q = 0; q < 8; ++q) hv[q] &= STRIPM;
                }
                __builtin_amdgcn_sched_barrier(0);
#pragma unroll
                for (int q = 0; q < 8; ++q) {
                    cvt_t c; c.u = hv[q];
                    if (q & 1) accB = __builtin_amdgcn_mfma_f32_32x32x16_f16(wf[8 + 8 * hh + q], c.h, accB, 0, 0, 0);
                    else       accA = __builtin_amdgcn_mfma_f32_32x32x16_f16(wf[8 + 8 * hh + q], c.h, accA, 0, 0, 0);
                }
            }
        }

        // ---- 4. K-split partials -> LDS ----
        {
            float* rw = red + wave * (OUTS * RED_STRIDE);
            int rb = hi << 2;
#pragma unroll
            for (int v = 0; v < 16; ++v) {
                int orow = (v & 3) + 8 * (v >> 2) + rb;
                rw[orow * RED_STRIDE + r] = accA[v] + accB[v];
            }
        }
        if constexpr (XF) barrier_lgkm_only();
        else              __syncthreads();

        // ---- 5. finish: reduce 4 partials + bias, fast tanh, tagged store ----
        {
            const u32 wtag = (u32)(((t + 1) >> 1) & 1);
            char* hob = (char*)hpack + (size_t)(((t + 1) & 1) * NGROUP + g) * HP_GROUP + foff;
            union { f16 h4[4]; uint2 u; } uu;
#pragma unroll
            for (int i = 0; i < 4; ++i) {
                int o = o0 + i;
                float p = blds[o];
#pragma unroll
                for (int w2 = 0; w2 < 4; ++w2)
                    p += red[w2 * (OUTS * RED_STRIDE) + o * RED_STRIDE + b_];
                // tanh(p) = 1 - 2/(e^{2p}+1); |result| <= 1 so f16 bit14 == 0
                float e = __expf(2.f * p);
                uu.h4[i] = (f16)(1.f - 2.f / (e + 1.f));
            }
            if (wtag) { uu.u.x |= TAGBITS; uu.u.y |= TAGBITS; }
            hstore8(hob, uu.u);
        }
        // end-of-step barrier: protects red[] WAR and xlds buffer swap.
        // Tags make vmcnt-draining unnecessary (stores carry their own tags).
        barrier_lgkm_only();
    }
}

// ---- classify: block per class, thread per batch row (packed buf 0) ----
__global__ void __launch_bounds__(256) classify_kernel(const f16* __restrict__ hpack,
                                                       const float* __restrict__ Wc,
                                                       const float* __restrict__ bc,
                                                       float* __restrict__ out) {
    __shared__ float wrow[DH];
    int c = blockIdx.x;
    int tid = threadIdx.x;
    for (int i = tid; i < DH; i += 256) wrow[i] = Wc[(size_t)c * DH + i];
    __syncthreads();
    int g = tid >> 5, r2 = tid & 31;
    const char* base = (const char*)hpack + (size_t)g * HP_GROUP;   // buffer 0
    float acc = bc[c];
    for (int j = 0; j < 64; ++j) {
#pragma unroll
        for (int h2 = 0; h2 < 2; ++h2) {
            f16x8 hv = *(const f16x8*)(base + j * 1024 + ((h2 << 5) + r2) * 16);
            int k = j * 16 + h2 * 8;
#pragma unroll
            for (int v = 0; v < 8; ++v) acc += (float)hv[v] * wrow[k + v];
        }
    }
    out[(size_t)tid * NCLS + c] = acc;
}

extern "C" void kernel_launch(void* const* d_in, const int* in_sizes, int n_in,
                              void* d_out, int out_size, void* d_ws, size_t ws_size,
                              hipStream_t stream) {
    const float* x  = (const float*)d_in[0];
    const float* W  = (const float*)d_in[1];
    const float* b  = (const float*)d_in[2];
    const float* Wc = (const float*)d_in[3];
    const float* bc = (const float*)d_in[4];
    float* out = (float*)d_out;

    char* ws = (char*)d_ws;
    f16* Wf     = (f16*)(ws + WF_OFF);
    f16* hpack  = (f16*)(ws + HP_OFF);
    int* xslots = (int*)(ws + SLOT_OFF);
    f16* xf     = (f16*)(ws + XF_OFF);

    const bool bigws = (ws_size >= WS_NEED);

    // buffer 0: zeros = h0 (valid, tag 0).  buffer 1: 0x4040 = stale (bit14
    // set) for the first tag-0 read at t=1.  Slot counters zeroed.  Every call.
    hipMemsetAsync(hpack, 0, HP_HALF, stream);
    hipMemsetAsync((char*)hpack + HP_HALF, 0x40, HP_HALF, stream);
    hipMemsetAsync(xslots, 0, SLOT_BYTES, stream);

    convert_W_kernel<<<(DH * DK + 255) / 256, 256, 0, stream>>>(W, Wf);
    if (bigws)
        convert_x_kernel<<<dim3(SEQ * NGROUP), dim3(256), 0, stream>>>(x, xf);

    const void* kfn = bigws ? (const void*)rnn_kernel<true>
                            : (const void*)rnn_kernel<false>;
    hipFuncSetAttribute(kfn, hipFuncAttributeMaxDynamicSharedMemorySize, SMEM_ALLOC);
    void* args[6];
    args[0] = (void*)&x;
    args[1] = (void*)&b;
    args[2] = (void*)&Wf;
    args[3] = (void*)&xf;
    args[4] = (void*)&hpack;
    args[5] = (void*)&xslots;
    hipLaunchCooperativeKernel(kfn, dim3(256), dim3(256), args, SMEM_ALLOC, stream);

    // final h in packed buffer 0 (step 511 writes buf (512)&1 = 0, tag 0 clean)
    classify_kernel<<<dim3(NCLS), dim3(256), 0, stream>>>(hpack, Wc, bc, out);
}